// Round 1
// 858.943 us; speedup vs baseline: 1.1212x; 1.1212x over previous
//
#include <hip/hip_runtime.h>
#include <hip/hip_bf16.h>

#define D 128
#define CAP 40

typedef __attribute__((ext_vector_type(8))) short bf16x8;
typedef __attribute__((ext_vector_type(4))) float f32x4;

__device__ __forceinline__ void atomAddF(float* p, float v) { unsafeAtomicAdd(p, v); }

__device__ __forceinline__ unsigned short f2bf(float f) {
    __hip_bfloat16 h = __float2bfloat16(f);
    return *reinterpret_cast<unsigned short*>(&h);
}
__device__ __forceinline__ float bf2f(unsigned int u16) {
    unsigned int x = u16 << 16;
    return *reinterpret_cast<float*>(&x);
}

// ---------------- cast fp32 -> bf16, 4 elems/thread ----------------
__global__ void cast_bf16(const float* __restrict__ in, unsigned short* __restrict__ out, long n4) {
    long i = (long)blockIdx.x * blockDim.x + threadIdx.x;
    if (i >= n4) return;
    float4 v = ((const float4*)in)[i];
    ushort4 o;
    o.x = f2bf(v.x); o.y = f2bf(v.y); o.z = f2bf(v.z); o.w = f2bf(v.w);
    ((ushort4*)out)[i] = o;
}

// ---------------- weights: cast + transpose (Wt[n*128+k] = W[k*128+n]) ----------------
__global__ void prep_weights(const float* __restrict__ Wra, const float* __restrict__ Wrg,
                             const float* __restrict__ Wrt, const float* __restrict__ Wroot_t,
                             const float* __restrict__ Wroot_a, const float* __restrict__ Wroot_g,
                             const float* __restrict__ ba, const float* __restrict__ bg,
                             unsigned short* __restrict__ Wt_adj, unsigned short* __restrict__ Wt_g,
                             unsigned short* __restrict__ Wt_t, unsigned short* __restrict__ Wt_root_t,
                             unsigned short* __restrict__ Wt_sum, float* __restrict__ bsum) {
    int i = blockIdx.x * blockDim.x + threadIdx.x;
    if (i < D * D) {
        int k = i >> 7, n = i & 127;
        int ti = n * D + k;
        Wt_adj[ti]    = f2bf(Wra[i]);
        Wt_g[ti]      = f2bf(Wrg[i]);
        Wt_t[ti]      = f2bf(Wrt[i]);
        Wt_root_t[ti] = f2bf(Wroot_t[i]);
        Wt_sum[ti]    = f2bf(Wroot_a[i] + Wroot_g[i]);
    }
    if (i < D) bsum[i] = ba[i] + bg[i];
}

// ---------------- bucket build ----------------
__global__ void fill_buckets(const int* __restrict__ src, const int* __restrict__ dst, int E,
                             int* __restrict__ cnt, int* __restrict__ buckets,
                             int* __restrict__ ovf, int* __restrict__ ovf_cnt) {
    int e = blockIdx.x * blockDim.x + threadIdx.x;
    if (e >= E) return;
    int d = dst[e];
    int p = atomicAdd(&cnt[d], 1);
    if (p < CAP) buckets[(long)d * CAP + p] = src[e];
    else         ovf[atomicAdd(ovf_cnt, 1)] = e;
}

// ---------------- pull-aggregate (bf16): agg[d] = sum y[src_e], no atomics ----------------
// one wave per dst row; lane holds 2 columns (bf16x2 = 1 dword)
__launch_bounds__(256)
__global__ void pull_agg(const unsigned short* __restrict__ y,
                         const int* __restrict__ cnt, const int* __restrict__ buckets,
                         const int* __restrict__ src, const int* __restrict__ dst,
                         const int* __restrict__ ovf, const int* __restrict__ ovf_cnt,
                         unsigned short* __restrict__ agg, int N) {
    int wid = (int)(((long)blockIdx.x * blockDim.x + threadIdx.x) >> 6);
    int lane = threadIdx.x & 63;
    if (wid >= N) return;
    int m = cnt[wid];
    int mc = m > CAP ? CAP : m;
    int idx = (lane < mc) ? buckets[(long)wid * CAP + lane] : 0;
    float accx = 0.f, accy = 0.f;
    for (int j = 0; j < mc; ++j) {
        int s = __shfl(idx, j, 64);
        unsigned int raw = *(const unsigned int*)(y + (long)s * D + lane * 2);
        accx += bf2f(raw & 0xffffu);
        accy += bf2f(raw >> 16);
    }
    if (m > CAP) {                       // rare path: exact via overflow list scan
        int oc = *ovf_cnt;
        for (int i = 0; i < oc; ++i) {
            int e = ovf[i];
            if (dst[e] == wid) {
                int s = src[e];
                unsigned int raw = *(const unsigned int*)(y + (long)s * D + lane * 2);
                accx += bf2f(raw & 0xffffu);
                accy += bf2f(raw >> 16);
            }
        }
    }
    unsigned int o = (unsigned int)f2bf(accx) | ((unsigned int)f2bf(accy) << 16);
    *(unsigned int*)(agg + (long)wid * D + lane * 2) = o;
}

// ---------------- fused MFMA GEMM, LDS-staged (m97-style 2-phase) ----------------
// out = sum_t A_t @ W_t + bias, + column stats.
// block 256 = 4 waves; block tile = 128 rows x 128 cols; wave = 32 rows x 128 cols.
// Per (term, ks) step: stage A-slice (128x32 bf16 = 8KB) + B-slice (128x32 = 8KB)
// into LDS via global_load_lds(16B), double-buffered. LDS slot permutation
//   slot(row,q4) = row*4 + (q4 ^ ((row>>2)&3))           (16B slots)
// gives dense 16-line staging reads AND 2-lanes/bank (free) ds_read_b128.
__launch_bounds__(256, 4)
__global__ void gemm_fused(int N,
                           const unsigned short* __restrict__ A0, const unsigned short* __restrict__ Wt0,
                           const unsigned short* __restrict__ A1, const unsigned short* __restrict__ Wt1,
                           const unsigned short* __restrict__ A2, const unsigned short* __restrict__ Wt2,
                           int nTerms,
                           const float* __restrict__ bias, float* __restrict__ out,
                           float* __restrict__ gsum, float* __restrict__ gsq) {
    __shared__ unsigned short lds[2][8192];   // per buf: A slots 0..511 (8KB), B slots at +4096 (8KB)
    __shared__ float sstat[256];
    const int tx = threadIdx.x;
    sstat[tx] = 0.f;

    const int wave = tx >> 6, lane = tx & 63;
    const int quad = lane >> 4, l16 = lane & 15;
    const int row0 = blockIdx.x * 128;

    // staging geometry: thread stages slots {tx, tx+256} of A and of B
    const int sA0 = tx, sA1 = tx + 256;
    const int rS0 = sA0 >> 2, qS0 = (sA0 & 3) ^ ((sA0 >> 4) & 3);
    const int rS1 = sA1 >> 2, qS1 = (sA1 & 3) ^ ((sA1 >> 4) & 3);
    long gr0 = (long)row0 + rS0; if (gr0 >= N) gr0 = N - 1;   // clamp ragged tail (epilogue guards exactness)
    long gr1 = (long)row0 + rS1; if (gr1 >= N) gr1 = N - 1;

    f32x4 acc[2][8];
#pragma unroll
    for (int rt = 0; rt < 2; ++rt)
#pragma unroll
        for (int ct = 0; ct < 8; ++ct)
#pragma unroll
            for (int i = 0; i < 4; ++i) acc[rt][ct][i] = 0.f;

    auto stage = [&](int s, int bb) {
        const int t = s >> 2;
        const int k0 = (s & 3) * 32;
        const unsigned short* A = (t == 0) ? A0 : ((t == 1) ? A1 : A2);
        const unsigned short* W = (t == 0) ? Wt0 : ((t == 1) ? Wt1 : Wt2);
        __builtin_amdgcn_global_load_lds(
            (const __attribute__((address_space(1))) unsigned int*)(A + gr0 * D + k0 + qS0 * 8),
            (__attribute__((address_space(3))) unsigned int*)(&lds[bb][sA0 * 8]), 16, 0, 0);
        __builtin_amdgcn_global_load_lds(
            (const __attribute__((address_space(1))) unsigned int*)(A + gr1 * D + k0 + qS1 * 8),
            (__attribute__((address_space(3))) unsigned int*)(&lds[bb][sA1 * 8]), 16, 0, 0);
        __builtin_amdgcn_global_load_lds(
            (const __attribute__((address_space(1))) unsigned int*)(W + (long)rS0 * D + k0 + qS0 * 8),
            (__attribute__((address_space(3))) unsigned int*)(&lds[bb][4096 + sA0 * 8]), 16, 0, 0);
        __builtin_amdgcn_global_load_lds(
            (const __attribute__((address_space(1))) unsigned int*)(W + (long)rS1 * D + k0 + qS1 * 8),
            (__attribute__((address_space(3))) unsigned int*)(&lds[bb][4096 + sA1 * 8]), 16, 0, 0);
    };

    const int xq = (l16 >> 2) & 3;       // read-side XOR term (uniform across fragments)
    const int qx = quad ^ xq;

    auto compute = [&](int cb) {
        const int slotA0 = (wave * 32 + l16) * 4 + qx;
        const int slotA1 = (wave * 32 + 16 + l16) * 4 + qx;
        bf16x8 a0 = *(const bf16x8*)&lds[cb][slotA0 * 8];
        bf16x8 a1 = *(const bf16x8*)&lds[cb][slotA1 * 8];
#pragma unroll
        for (int ct = 0; ct < 8; ++ct) {
            const int slotB = (ct * 16 + l16) * 4 + qx;
            bf16x8 b = *(const bf16x8*)&lds[cb][4096 + slotB * 8];
            acc[0][ct] = __builtin_amdgcn_mfma_f32_16x16x32_bf16(a0, b, acc[0][ct], 0, 0, 0);
            acc[1][ct] = __builtin_amdgcn_mfma_f32_16x16x32_bf16(a1, b, acc[1][ct], 0, 0, 0);
        }
    };

    const int nsteps = nTerms * 4;
    stage(0, 0);
    __syncthreads();                      // drains vmcnt(0): buf0 ready; sstat init visible
    for (int s = 0; s < nsteps; ++s) {
        const int cb = s & 1;
        if (s + 1 < nsteps) stage(s + 1, cb ^ 1);   // issue prefetch BEFORE compute
        compute(cb);
        __syncthreads();                  // next buf staged + this buf free for overwrite
    }

    // epilogue: bias, store, per-column partial stats
    float bv[8];
#pragma unroll
    for (int ct = 0; ct < 8; ++ct) bv[ct] = bias[ct * 16 + l16];

    float psum[8], psq[8];
#pragma unroll
    for (int ct = 0; ct < 8; ++ct) { psum[ct] = 0.f; psq[ct] = 0.f; }

#pragma unroll
    for (int rt = 0; rt < 2; ++rt)
#pragma unroll
        for (int i = 0; i < 4; ++i) {
            int row = row0 + wave * 32 + rt * 16 + quad * 4 + i;
            if (row < N) {
#pragma unroll
                for (int ct = 0; ct < 8; ++ct) {
                    float v = acc[rt][ct][i] + bv[ct];
                    out[(size_t)row * D + ct * 16 + l16] = v;
                    psum[ct] += v;
                    psq[ct] += v * v;
                }
            }
        }

#pragma unroll
    for (int ct = 0; ct < 8; ++ct) {
        atomicAdd(&sstat[ct * 16 + l16], psum[ct]);
        atomicAdd(&sstat[128 + ct * 16 + l16], psq[ct]);
    }
    __syncthreads();
    if (tx < 128) {
        atomAddF(&gsum[tx], sstat[tx]);
        atomAddF(&gsq[tx], sstat[128 + tx]);
    }
}

// ---------------- stats -> scale/shift ----------------
__global__ void finalize_stats(const float* __restrict__ stats,
                               const float* __restrict__ wv, const float* __restrict__ bv, const float* __restrict__ msv,
                               const float* __restrict__ wc, const float* __restrict__ bc, const float* __restrict__ msc,
                               int Nvar, int Ncon,
                               float* __restrict__ scale_var, float* __restrict__ shift_var,
                               float* __restrict__ scale_con, float* __restrict__ shift_con) {
    int tx = threadIdx.x;
    if (tx < 128) {
        float n = (float)Nvar;
        float mu = stats[tx] / n;
        float ex2 = stats[128 + tx] / n;
        float ms = msv[tx];
        float var = ex2 - 2.f * ms * mu * mu + ms * ms * mu * mu;
        float istd = rsqrtf(var + 1e-5f);
        float sc = wv[tx] * istd;
        scale_var[tx] = sc;
        shift_var[tx] = bv[tx] - sc * ms * mu;
    } else if (tx < 256) {
        int t = tx - 128;
        float n = (float)Ncon;
        float mu = stats[256 + t] / n;
        float ex2 = stats[384 + t] / n;
        float ms = msc[t];
        float var = ex2 - 2.f * ms * mu * mu + ms * ms * mu * mu;
        float istd = rsqrtf(var + 1e-5f);
        float sc = wc[t] * istd;
        scale_con[t] = sc;
        shift_con[t] = bc[t] - sc * ms * mu;
    }
}

// ---------------- in-place normalize + relu ----------------
__global__ void norm_relu(float* __restrict__ buf,
                          const float* __restrict__ scale, const float* __restrict__ shift,
                          long nvec) {
    long i = (long)blockIdx.x * blockDim.x + threadIdx.x;
    if (i >= nvec) return;
    int q = ((int)i & 31) * 4;
    float4 v = *(float4*)(buf + i * 4);
    float4 o;
    o.x = fmaxf(0.f, v.x * scale[q + 0] + shift[q + 0]);
    o.y = fmaxf(0.f, v.y * scale[q + 1] + shift[q + 1]);
    o.z = fmaxf(0.f, v.z * scale[q + 2] + shift[q + 2]);
    o.w = fmaxf(0.f, v.w * scale[q + 3] + shift[q + 3]);
    *(float4*)(buf + i * 4) = o;
}

extern "C" void kernel_launch(void* const* d_in, const int* in_sizes, int n_in,
                              void* d_out, int out_size, void* d_ws, size_t ws_size,
                              hipStream_t stream) {
    const float* x_var = (const float*)d_in[0];
    const float* x_con = (const float*)d_in[1];
    const float* x_reg = (const float*)d_in[2];
    const int* src_adj = (const int*)d_in[3];
    const int* dst_adj = (const int*)d_in[4];
    const int* src_t   = (const int*)d_in[5];
    const int* dst_t   = (const int*)d_in[6];
    const int* src_g   = (const int*)d_in[7];
    const int* dst_g   = (const int*)d_in[8];
    const float* W_rel_adj  = (const float*)d_in[9];
    const float* b_adj      = (const float*)d_in[10];
    const float* W_root_adj = (const float*)d_in[11];
    const float* W_rel_t    = (const float*)d_in[12];
    const float* b_t        = (const float*)d_in[13];
    const float* W_root_t   = (const float*)d_in[14];
    const float* W_rel_g    = (const float*)d_in[15];
    const float* b_g        = (const float*)d_in[16];
    const float* W_root_g   = (const float*)d_in[17];
    const float* gnw_v  = (const float*)d_in[18];
    const float* gnb_v  = (const float*)d_in[19];
    const float* gnms_v = (const float*)d_in[20];
    const float* gnw_c  = (const float*)d_in[21];
    const float* gnb_c  = (const float*)d_in[22];
    const float* gnms_c = (const float*)d_in[23];

    const int Nvar = in_sizes[0] / D;
    const int Ncon = in_sizes[1] / D;
    const int Nreg = in_sizes[2] / D;
    const int Eadj = in_sizes[3];
    const int Et   = in_sizes[5];
    const int Eg   = in_sizes[7];
    const int Emax = Eadj > Et ? (Eadj > Eg ? Eadj : Eg) : (Et > Eg ? Et : Eg);

    // ---- workspace layout (large blocks first, all 256B-aligned) ----
    char* p = (char*)d_ws;
    unsigned short* xv_bf = (unsigned short*)p; p += (size_t)Nvar * D * 2;
    unsigned short* xc_bf = (unsigned short*)p; p += (size_t)Ncon * D * 2;
    unsigned short* xr_bf = (unsigned short*)p; p += (size_t)Nreg * D * 2;
    unsigned short* agg_adj = (unsigned short*)p; p += (size_t)Nvar * D * 2;
    unsigned short* agg_g   = (unsigned short*)p; p += (size_t)Nvar * D * 2;
    unsigned short* agg_t   = (unsigned short*)p; p += (size_t)Ncon * D * 2;
    int* buckets = (int*)p; p += (size_t)Nvar * CAP * 4;
    int* ovf     = (int*)p; p += (size_t)Emax * 4;
    int* cnt     = (int*)p; p += (size_t)Nvar * 4;
    unsigned short* Wt_adj    = (unsigned short*)p; p += D * D * 2;
    unsigned short* Wt_g      = (unsigned short*)p; p += D * D * 2;
    unsigned short* Wt_t      = (unsigned short*)p; p += D * D * 2;
    unsigned short* Wt_root_t = (unsigned short*)p; p += D * D * 2;
    unsigned short* Wt_sum    = (unsigned short*)p; p += D * D * 2;
    float* bsum  = (float*)p; p += D * 4;
    float* stats = (float*)p; p += 512 * 4;
    float* scale_var = (float*)p; p += D * 4;
    float* shift_var = (float*)p; p += D * 4;
    float* scale_con = (float*)p; p += D * 4;
    float* shift_con = (float*)p; p += D * 4;
    int* ovf_cnt = (int*)p; p += 256;

    float* out_var = (float*)d_out;
    float* out_con = out_var + (size_t)Nvar * D;

    hipMemsetAsync(stats, 0, 512 * sizeof(float), stream);
    prep_weights<<<64, 256, 0, stream>>>(W_rel_adj, W_rel_g, W_rel_t, W_root_t,
                                         W_root_adj, W_root_g, b_adj, b_g,
                                         Wt_adj, Wt_g, Wt_t, Wt_root_t, Wt_sum, bsum);

    cast_bf16<<<(int)(((long)Nvar * 32 + 255) / 256), 256, 0, stream>>>(x_var, xv_bf, (long)Nvar * 32);
    cast_bf16<<<(int)(((long)Ncon * 32 + 255) / 256), 256, 0, stream>>>(x_con, xc_bf, (long)Ncon * 32);
    cast_bf16<<<(int)(((long)Nreg * 32 + 255) / 256), 256, 0, stream>>>(x_reg, xr_bf, (long)Nreg * 32);

    struct G { const unsigned short* xs; const int* src; const int* dst; int E; int Ndst; unsigned short* agg; };
    G graphs[3] = {
        { xv_bf, src_adj, dst_adj, Eadj, Nvar, agg_adj },
        { xr_bf, src_g,   dst_g,   Eg,   Nvar, agg_g   },
        { xv_bf, src_t,   dst_t,   Et,   Ncon, agg_t   },
    };

    for (int gi = 0; gi < 3; ++gi) {
        G& g = graphs[gi];
        hipMemsetAsync(cnt, 0, (size_t)g.Ndst * sizeof(int), stream);
        hipMemsetAsync(ovf_cnt, 0, sizeof(int), stream);
        fill_buckets<<<(g.E + 255) / 256, 256, 0, stream>>>(g.src, g.dst, g.E, cnt, buckets, ovf, ovf_cnt);
        long T = (long)g.Ndst * 64;
        pull_agg<<<(int)((T + 255) / 256), 256, 0, stream>>>(g.xs, cnt, buckets,
                                                             g.src, g.dst, ovf, ovf_cnt,
                                                             g.agg, g.Ndst);
    }

    gemm_fused<<<(Nvar + 127) / 128, 256, 0, stream>>>(Nvar,
        agg_adj, Wt_adj, agg_g, Wt_g, xv_bf, Wt_sum, 3,
        bsum, out_var, stats, stats + 128);
    gemm_fused<<<(Ncon + 127) / 128, 256, 0, stream>>>(Ncon,
        agg_t, Wt_t, xc_bf, Wt_root_t, nullptr, nullptr, 2,
        b_t, out_con, stats + 256, stats + 384);

    finalize_stats<<<1, 256, 0, stream>>>(stats,
        gnw_v, gnb_v, gnms_v, gnw_c, gnb_c, gnms_c,
        Nvar, Ncon, scale_var, shift_var, scale_con, shift_con);

    {
        long nvec = (long)Nvar * 32;
        norm_relu<<<(int)((nvec + 255) / 256), 256, 0, stream>>>(out_var, scale_var, shift_var, nvec);
    }
    {
        long nvec = (long)Ncon * 32;
        norm_relu<<<(int)((nvec + 255) / 256), 256, 0, stream>>>(out_con, scale_con, shift_con, nvec);
    }
}

// Round 2
// 809.127 us; speedup vs baseline: 1.1903x; 1.0616x over previous
//
#include <hip/hip_runtime.h>
#include <hip/hip_bf16.h>

#define D 128
#define CAP 40

typedef __attribute__((ext_vector_type(8))) short bf16x8;
typedef __attribute__((ext_vector_type(4))) float f32x4;

__device__ __forceinline__ void atomAddF(float* p, float v) { unsafeAtomicAdd(p, v); }

__device__ __forceinline__ unsigned short f2bf(float f) {
    __hip_bfloat16 h = __float2bfloat16(f);
    return *reinterpret_cast<unsigned short*>(&h);
}
__device__ __forceinline__ float bf2f(unsigned int u16) {
    unsigned int x = u16 << 16;
    return *reinterpret_cast<float*>(&x);
}

// ---------------- cast fp32 -> bf16, 4 elems/thread ----------------
__global__ void cast_bf16(const float* __restrict__ in, unsigned short* __restrict__ out, long n4) {
    long i = (long)blockIdx.x * blockDim.x + threadIdx.x;
    if (i >= n4) return;
    float4 v = ((const float4*)in)[i];
    ushort4 o;
    o.x = f2bf(v.x); o.y = f2bf(v.y); o.z = f2bf(v.z); o.w = f2bf(v.w);
    ((ushort4*)out)[i] = o;
}

// ---------------- weights: cast + transpose (Wt[n*128+k] = W[k*128+n]) ----------------
__global__ void prep_weights(const float* __restrict__ Wra, const float* __restrict__ Wrg,
                             const float* __restrict__ Wrt, const float* __restrict__ Wroot_t,
                             const float* __restrict__ Wroot_a, const float* __restrict__ Wroot_g,
                             const float* __restrict__ ba, const float* __restrict__ bg,
                             unsigned short* __restrict__ Wt_adj, unsigned short* __restrict__ Wt_g,
                             unsigned short* __restrict__ Wt_t, unsigned short* __restrict__ Wt_root_t,
                             unsigned short* __restrict__ Wt_sum, float* __restrict__ bsum) {
    int i = blockIdx.x * blockDim.x + threadIdx.x;
    if (i < D * D) {
        int k = i >> 7, n = i & 127;
        int ti = n * D + k;
        Wt_adj[ti]    = f2bf(Wra[i]);
        Wt_g[ti]      = f2bf(Wrg[i]);
        Wt_t[ti]      = f2bf(Wrt[i]);
        Wt_root_t[ti] = f2bf(Wroot_t[i]);
        Wt_sum[ti]    = f2bf(Wroot_a[i] + Wroot_g[i]);
    }
    if (i < D) bsum[i] = ba[i] + bg[i];
}

// ---------------- bucket build ----------------
__global__ void fill_buckets(const int* __restrict__ src, const int* __restrict__ dst, int E,
                             int* __restrict__ cnt, int* __restrict__ buckets,
                             int* __restrict__ ovf, int* __restrict__ ovf_cnt) {
    int e = blockIdx.x * blockDim.x + threadIdx.x;
    if (e >= E) return;
    int d = dst[e];
    int p = atomicAdd(&cnt[d], 1);
    if (p < CAP) buckets[(long)d * CAP + p] = src[e];
    else         ovf[atomicAdd(ovf_cnt, 1)] = e;
}

// ---------------- pull-aggregate (bf16): agg[d] = sum y[src_e], no atomics ----------------
// one wave per dst row. MLP-optimized: two 32-lane halves each gather a DIFFERENT
// edge's source row (lane = uint2 = 4 cols), unrolled x2 -> 4 rows in flight/wave.
__launch_bounds__(256)
__global__ void pull_agg(const unsigned short* __restrict__ y,
                         const int* __restrict__ cnt, const int* __restrict__ buckets,
                         const int* __restrict__ src, const int* __restrict__ dst,
                         const int* __restrict__ ovf, const int* __restrict__ ovf_cnt,
                         unsigned short* __restrict__ agg, int N) {
    int wid = (int)(((long)blockIdx.x * blockDim.x + threadIdx.x) >> 6);
    int lane = threadIdx.x & 63;
    if (wid >= N) return;
    const int half = lane >> 5;          // 0: even edge of pair, 1: odd edge
    const int hl = lane & 31;            // column group: cols [hl*4 .. hl*4+3]
    const long colOff = (long)hl * 4;

    int m = cnt[wid];
    int mc = m > CAP ? CAP : m;
    int idx = (lane < mc) ? buckets[(long)wid * CAP + lane] : 0;

    float acc0 = 0.f, acc1 = 0.f, acc2 = 0.f, acc3 = 0.f;

    for (int j = 0; j < mc; j += 4) {
        int e0 = j + half;               // batch slot 0 (edges j, j+1)
        int e1 = j + 2 + half;           // batch slot 1 (edges j+2, j+3)
        int s0 = __shfl(idx, e0, 64);    // e_k <= CAP+2 < 64; inactive slots -> row 0 (valid addr)
        int s1 = __shfl(idx, e1, 64);
        uint2 r0 = *(const uint2*)(y + (long)s0 * D + colOff);
        uint2 r1 = *(const uint2*)(y + (long)s1 * D + colOff);
        if (e0 >= mc) { r0.x = 0u; r0.y = 0u; }   // branchless cndmask; bf16 0-bits == 0.0f
        if (e1 >= mc) { r1.x = 0u; r1.y = 0u; }
        acc0 += bf2f(r0.x & 0xffffu) + bf2f(r1.x & 0xffffu);
        acc1 += bf2f(r0.x >> 16)     + bf2f(r1.x >> 16);
        acc2 += bf2f(r0.y & 0xffffu) + bf2f(r1.y & 0xffffu);
        acc3 += bf2f(r0.y >> 16)     + bf2f(r1.y >> 16);
    }

    if (m > CAP) {                       // rare path: exact via overflow list scan
        int oc = *ovf_cnt;
        for (int i = 0; i < oc; ++i) {
            int e = ovf[i];
            if (dst[e] == wid && half == 0) {   // count once (halves are summed below)
                int s = src[e];
                uint2 r = *(const uint2*)(y + (long)s * D + colOff);
                acc0 += bf2f(r.x & 0xffffu);
                acc1 += bf2f(r.x >> 16);
                acc2 += bf2f(r.y & 0xffffu);
                acc3 += bf2f(r.y >> 16);
            }
        }
    }

    // combine the two halves (lane <-> lane+32)
    acc0 += __shfl_xor(acc0, 32, 64);
    acc1 += __shfl_xor(acc1, 32, 64);
    acc2 += __shfl_xor(acc2, 32, 64);
    acc3 += __shfl_xor(acc3, 32, 64);

    if (half == 0) {
        uint2 o;
        o.x = (unsigned int)f2bf(acc0) | ((unsigned int)f2bf(acc1) << 16);
        o.y = (unsigned int)f2bf(acc2) | ((unsigned int)f2bf(acc3) << 16);
        *(uint2*)(agg + (long)wid * D + colOff) = o;
    }
}

// ---------------- fused MFMA GEMM, LDS-staged (m97-style 2-phase) ----------------
// out = sum_t A_t @ W_t + bias, + column stats.
// block 256 = 4 waves; block tile = 128 rows x 128 cols; wave = 32 rows x 128 cols.
// Per (term, ks) step: stage A-slice (128x32 bf16 = 8KB) + B-slice (128x32 = 8KB)
// into LDS via global_load_lds(16B), double-buffered. LDS slot permutation
//   slot(row,q4) = row*4 + (q4 ^ ((row>>2)&3))           (16B slots)
// gives dense 16-line staging reads AND 2-lanes/bank (free) ds_read_b128.
__launch_bounds__(256, 4)
__global__ void gemm_fused(int N,
                           const unsigned short* __restrict__ A0, const unsigned short* __restrict__ Wt0,
                           const unsigned short* __restrict__ A1, const unsigned short* __restrict__ Wt1,
                           const unsigned short* __restrict__ A2, const unsigned short* __restrict__ Wt2,
                           int nTerms,
                           const float* __restrict__ bias, float* __restrict__ out,
                           float* __restrict__ gsum, float* __restrict__ gsq) {
    __shared__ unsigned short lds[2][8192];   // per buf: A slots 0..511 (8KB), B slots at +4096 (8KB)
    __shared__ float sstat[256];
    const int tx = threadIdx.x;
    sstat[tx] = 0.f;

    const int wave = tx >> 6, lane = tx & 63;
    const int quad = lane >> 4, l16 = lane & 15;
    const int row0 = blockIdx.x * 128;

    // staging geometry: thread stages slots {tx, tx+256} of A and of B
    const int sA0 = tx, sA1 = tx + 256;
    const int rS0 = sA0 >> 2, qS0 = (sA0 & 3) ^ ((sA0 >> 4) & 3);
    const int rS1 = sA1 >> 2, qS1 = (sA1 & 3) ^ ((sA1 >> 4) & 3);
    long gr0 = (long)row0 + rS0; if (gr0 >= N) gr0 = N - 1;   // clamp ragged tail (epilogue guards exactness)
    long gr1 = (long)row0 + rS1; if (gr1 >= N) gr1 = N - 1;

    f32x4 acc[2][8];
#pragma unroll
    for (int rt = 0; rt < 2; ++rt)
#pragma unroll
        for (int ct = 0; ct < 8; ++ct)
#pragma unroll
            for (int i = 0; i < 4; ++i) acc[rt][ct][i] = 0.f;

    auto stage = [&](int s, int bb) {
        const int t = s >> 2;
        const int k0 = (s & 3) * 32;
        const unsigned short* A = (t == 0) ? A0 : ((t == 1) ? A1 : A2);
        const unsigned short* W = (t == 0) ? Wt0 : ((t == 1) ? Wt1 : Wt2);
        __builtin_amdgcn_global_load_lds(
            (const __attribute__((address_space(1))) unsigned int*)(A + gr0 * D + k0 + qS0 * 8),
            (__attribute__((address_space(3))) unsigned int*)(&lds[bb][sA0 * 8]), 16, 0, 0);
        __builtin_amdgcn_global_load_lds(
            (const __attribute__((address_space(1))) unsigned int*)(A + gr1 * D + k0 + qS1 * 8),
            (__attribute__((address_space(3))) unsigned int*)(&lds[bb][sA1 * 8]), 16, 0, 0);
        __builtin_amdgcn_global_load_lds(
            (const __attribute__((address_space(1))) unsigned int*)(W + (long)rS0 * D + k0 + qS0 * 8),
            (__attribute__((address_space(3))) unsigned int*)(&lds[bb][4096 + sA0 * 8]), 16, 0, 0);
        __builtin_amdgcn_global_load_lds(
            (const __attribute__((address_space(1))) unsigned int*)(W + (long)rS1 * D + k0 + qS1 * 8),
            (__attribute__((address_space(3))) unsigned int*)(&lds[bb][4096 + sA1 * 8]), 16, 0, 0);
    };

    const int xq = (l16 >> 2) & 3;       // read-side XOR term (uniform across fragments)
    const int qx = quad ^ xq;

    auto compute = [&](int cb) {
        const int slotA0 = (wave * 32 + l16) * 4 + qx;
        const int slotA1 = (wave * 32 + 16 + l16) * 4 + qx;
        bf16x8 a0 = *(const bf16x8*)&lds[cb][slotA0 * 8];
        bf16x8 a1 = *(const bf16x8*)&lds[cb][slotA1 * 8];
#pragma unroll
        for (int ct = 0; ct < 8; ++ct) {
            const int slotB = (ct * 16 + l16) * 4 + qx;
            bf16x8 b = *(const bf16x8*)&lds[cb][4096 + slotB * 8];
            acc[0][ct] = __builtin_amdgcn_mfma_f32_16x16x32_bf16(a0, b, acc[0][ct], 0, 0, 0);
            acc[1][ct] = __builtin_amdgcn_mfma_f32_16x16x32_bf16(a1, b, acc[1][ct], 0, 0, 0);
        }
    };

    const int nsteps = nTerms * 4;
    stage(0, 0);
    __syncthreads();                      // drains vmcnt(0): buf0 ready; sstat init visible
    for (int s = 0; s < nsteps; ++s) {
        const int cb = s & 1;
        if (s + 1 < nsteps) stage(s + 1, cb ^ 1);   // issue prefetch BEFORE compute
        compute(cb);
        __syncthreads();                  // next buf staged + this buf free for overwrite
    }

    // epilogue: bias, store, per-column partial stats
    float bv[8];
#pragma unroll
    for (int ct = 0; ct < 8; ++ct) bv[ct] = bias[ct * 16 + l16];

    float psum[8], psq[8];
#pragma unroll
    for (int ct = 0; ct < 8; ++ct) { psum[ct] = 0.f; psq[ct] = 0.f; }

#pragma unroll
    for (int rt = 0; rt < 2; ++rt)
#pragma unroll
        for (int i = 0; i < 4; ++i) {
            int row = row0 + wave * 32 + rt * 16 + quad * 4 + i;
            if (row < N) {
#pragma unroll
                for (int ct = 0; ct < 8; ++ct) {
                    float v = acc[rt][ct][i] + bv[ct];
                    out[(size_t)row * D + ct * 16 + l16] = v;
                    psum[ct] += v;
                    psq[ct] += v * v;
                }
            }
        }

#pragma unroll
    for (int ct = 0; ct < 8; ++ct) {
        atomicAdd(&sstat[ct * 16 + l16], psum[ct]);
        atomicAdd(&sstat[128 + ct * 16 + l16], psq[ct]);
    }
    __syncthreads();
    if (tx < 128) {
        atomAddF(&gsum[tx], sstat[tx]);
        atomAddF(&gsq[tx], sstat[128 + tx]);
    }
}

// ---------------- stats -> scale/shift ----------------
__global__ void finalize_stats(const float* __restrict__ stats,
                               const float* __restrict__ wv, const float* __restrict__ bv, const float* __restrict__ msv,
                               const float* __restrict__ wc, const float* __restrict__ bc, const float* __restrict__ msc,
                               int Nvar, int Ncon,
                               float* __restrict__ scale_var, float* __restrict__ shift_var,
                               float* __restrict__ scale_con, float* __restrict__ shift_con) {
    int tx = threadIdx.x;
    if (tx < 128) {
        float n = (float)Nvar;
        float mu = stats[tx] / n;
        float ex2 = stats[128 + tx] / n;
        float ms = msv[tx];
        float var = ex2 - 2.f * ms * mu * mu + ms * ms * mu * mu;
        float istd = rsqrtf(var + 1e-5f);
        float sc = wv[tx] * istd;
        scale_var[tx] = sc;
        shift_var[tx] = bv[tx] - sc * ms * mu;
    } else if (tx < 256) {
        int t = tx - 128;
        float n = (float)Ncon;
        float mu = stats[256 + t] / n;
        float ex2 = stats[384 + t] / n;
        float ms = msc[t];
        float var = ex2 - 2.f * ms * mu * mu + ms * ms * mu * mu;
        float istd = rsqrtf(var + 1e-5f);
        float sc = wc[t] * istd;
        scale_con[t] = sc;
        shift_con[t] = bc[t] - sc * ms * mu;
    }
}

// ---------------- in-place normalize + relu ----------------
__global__ void norm_relu(float* __restrict__ buf,
                          const float* __restrict__ scale, const float* __restrict__ shift,
                          long nvec) {
    long i = (long)blockIdx.x * blockDim.x + threadIdx.x;
    if (i >= nvec) return;
    int q = ((int)i & 31) * 4;
    float4 v = *(float4*)(buf + i * 4);
    float4 o;
    o.x = fmaxf(0.f, v.x * scale[q + 0] + shift[q + 0]);
    o.y = fmaxf(0.f, v.y * scale[q + 1] + shift[q + 1]);
    o.z = fmaxf(0.f, v.z * scale[q + 2] + shift[q + 2]);
    o.w = fmaxf(0.f, v.w * scale[q + 3] + shift[q + 3]);
    *(float4*)(buf + i * 4) = o;
}

extern "C" void kernel_launch(void* const* d_in, const int* in_sizes, int n_in,
                              void* d_out, int out_size, void* d_ws, size_t ws_size,
                              hipStream_t stream) {
    const float* x_var = (const float*)d_in[0];
    const float* x_con = (const float*)d_in[1];
    const float* x_reg = (const float*)d_in[2];
    const int* src_adj = (const int*)d_in[3];
    const int* dst_adj = (const int*)d_in[4];
    const int* src_t   = (const int*)d_in[5];
    const int* dst_t   = (const int*)d_in[6];
    const int* src_g   = (const int*)d_in[7];
    const int* dst_g   = (const int*)d_in[8];
    const float* W_rel_adj  = (const float*)d_in[9];
    const float* b_adj      = (const float*)d_in[10];
    const float* W_root_adj = (const float*)d_in[11];
    const float* W_rel_t    = (const float*)d_in[12];
    const float* b_t        = (const float*)d_in[13];
    const float* W_root_t   = (const float*)d_in[14];
    const float* W_rel_g    = (const float*)d_in[15];
    const float* b_g        = (const float*)d_in[16];
    const float* W_root_g   = (const float*)d_in[17];
    const float* gnw_v  = (const float*)d_in[18];
    const float* gnb_v  = (const float*)d_in[19];
    const float* gnms_v = (const float*)d_in[20];
    const float* gnw_c  = (const float*)d_in[21];
    const float* gnb_c  = (const float*)d_in[22];
    const float* gnms_c = (const float*)d_in[23];

    const int Nvar = in_sizes[0] / D;
    const int Ncon = in_sizes[1] / D;
    const int Nreg = in_sizes[2] / D;
    const int Eadj = in_sizes[3];
    const int Et   = in_sizes[5];
    const int Eg   = in_sizes[7];
    const int Emax = Eadj > Et ? (Eadj > Eg ? Eadj : Eg) : (Et > Eg ? Et : Eg);

    // ---- workspace layout (large blocks first, all 256B-aligned) ----
    char* p = (char*)d_ws;
    unsigned short* xv_bf = (unsigned short*)p; p += (size_t)Nvar * D * 2;
    unsigned short* xc_bf = (unsigned short*)p; p += (size_t)Ncon * D * 2;
    unsigned short* xr_bf = (unsigned short*)p; p += (size_t)Nreg * D * 2;
    unsigned short* agg_adj = (unsigned short*)p; p += (size_t)Nvar * D * 2;
    unsigned short* agg_g   = (unsigned short*)p; p += (size_t)Nvar * D * 2;
    unsigned short* agg_t   = (unsigned short*)p; p += (size_t)Ncon * D * 2;
    int* buckets = (int*)p; p += (size_t)Nvar * CAP * 4;
    int* ovf     = (int*)p; p += (size_t)Emax * 4;
    int* cnt     = (int*)p; p += (size_t)Nvar * 4;
    unsigned short* Wt_adj    = (unsigned short*)p; p += D * D * 2;
    unsigned short* Wt_g      = (unsigned short*)p; p += D * D * 2;
    unsigned short* Wt_t      = (unsigned short*)p; p += D * D * 2;
    unsigned short* Wt_root_t = (unsigned short*)p; p += D * D * 2;
    unsigned short* Wt_sum    = (unsigned short*)p; p += D * D * 2;
    float* bsum  = (float*)p; p += D * 4;
    float* stats = (float*)p; p += 512 * 4;
    float* scale_var = (float*)p; p += D * 4;
    float* shift_var = (float*)p; p += D * 4;
    float* scale_con = (float*)p; p += D * 4;
    float* shift_con = (float*)p; p += D * 4;
    int* ovf_cnt = (int*)p; p += 256;

    float* out_var = (float*)d_out;
    float* out_con = out_var + (size_t)Nvar * D;

    hipMemsetAsync(stats, 0, 512 * sizeof(float), stream);
    prep_weights<<<64, 256, 0, stream>>>(W_rel_adj, W_rel_g, W_rel_t, W_root_t,
                                         W_root_adj, W_root_g, b_adj, b_g,
                                         Wt_adj, Wt_g, Wt_t, Wt_root_t, Wt_sum, bsum);

    cast_bf16<<<(int)(((long)Nvar * 32 + 255) / 256), 256, 0, stream>>>(x_var, xv_bf, (long)Nvar * 32);
    cast_bf16<<<(int)(((long)Ncon * 32 + 255) / 256), 256, 0, stream>>>(x_con, xc_bf, (long)Ncon * 32);
    cast_bf16<<<(int)(((long)Nreg * 32 + 255) / 256), 256, 0, stream>>>(x_reg, xr_bf, (long)Nreg * 32);

    struct G { const unsigned short* xs; const int* src; const int* dst; int E; int Ndst; unsigned short* agg; };
    G graphs[3] = {
        { xv_bf, src_adj, dst_adj, Eadj, Nvar, agg_adj },
        { xr_bf, src_g,   dst_g,   Eg,   Nvar, agg_g   },
        { xv_bf, src_t,   dst_t,   Et,   Ncon, agg_t   },
    };

    for (int gi = 0; gi < 3; ++gi) {
        G& g = graphs[gi];
        hipMemsetAsync(cnt, 0, (size_t)g.Ndst * sizeof(int), stream);
        hipMemsetAsync(ovf_cnt, 0, sizeof(int), stream);
        fill_buckets<<<(g.E + 255) / 256, 256, 0, stream>>>(g.src, g.dst, g.E, cnt, buckets, ovf, ovf_cnt);
        long T = (long)g.Ndst * 64;
        pull_agg<<<(int)((T + 255) / 256), 256, 0, stream>>>(g.xs, cnt, buckets,
                                                             g.src, g.dst, ovf, ovf_cnt,
                                                             g.agg, g.Ndst);
    }

    gemm_fused<<<(Nvar + 127) / 128, 256, 0, stream>>>(Nvar,
        agg_adj, Wt_adj, agg_g, Wt_g, xv_bf, Wt_sum, 3,
        bsum, out_var, stats, stats + 128);
    gemm_fused<<<(Ncon + 127) / 128, 256, 0, stream>>>(Ncon,
        agg_t, Wt_t, xc_bf, Wt_root_t, nullptr, nullptr, 2,
        b_t, out_con, stats + 256, stats + 384);

    finalize_stats<<<1, 256, 0, stream>>>(stats,
        gnw_v, gnb_v, gnms_v, gnw_c, gnb_c, gnms_c,
        Nvar, Ncon, scale_var, shift_var, scale_con, shift_con);

    {
        long nvec = (long)Nvar * 32;
        norm_relu<<<(int)((nvec + 255) / 256), 256, 0, stream>>>(out_var, scale_var, shift_var, nvec);
    }
    {
        long nvec = (long)Ncon * 32;
        norm_relu<<<(int)((nvec + 255) / 256), 256, 0, stream>>>(out_con, scale_con, shift_con, nvec);
    }
}